// Round 7
// baseline (83.158 us; speedup 1.0000x reference)
//
#include <hip/hip_runtime.h>

// E2M1 (MXFP4-style) activation quantizer, block size 32, LAYER_MAX = 6.0.
// Outputs concatenated in d_out as float32:
//   [0, N)        x_deq
//   [N, 2N)       encoded (values 0..15, stored as float)
//   [2N, 2N+N/32) scale_uint8 (values 0..255, stored as float)
//
// Memory pattern (round-6, 70.9us): 1x float4 per lane, line-dense coalesced;
// 8-lane group = one 32-elem quant block; nontemporal stores (write-once
// streams >> 32MB L2). Round-7 delta: nontemporal LOADS too (input is
// read-once; line-dense pattern makes evict-first safe, unlike round 5).

typedef float f32x4 __attribute__((ext_vector_type(4)));

constexpr int TPB = 256;

struct EncOut { float dq, ef; };

__device__ __forceinline__ EncOut enc1(float xv, float rscale, float scale) {
    const float axn = fabsf(xv) * rscale;   // exact: power-of-2 scale
    const int ord = (axn > 0.25f) + (axn > 0.75f) + (axn > 1.25f) +
                    (axn > 1.75f) + (axn > 2.5f)  + (axn > 3.5f) +
                    (axn > 5.0f);
    // E2M1 table {0,0.5,1,1.5,2,3,4,6} without runtime-indexed array
    const float m = (ord <= 4) ? (float)ord * 0.5f
                     : (ord == 5 ? 3.0f : (ord == 6 ? 4.0f : 6.0f));
    const bool pos = xv > 0.0f;             // sign_bit = 1 for x <= 0
    EncOut o;
    o.ef = (float)(pos ? ord : ord + 8);
    o.dq = (pos ? m : -m) * scale;
    return o;
}

__global__ __launch_bounds__(TPB) void e2m1_quant_kernel(
    const float* __restrict__ x,
    float* __restrict__ xdeq,
    float* __restrict__ enc,
    float* __restrict__ scl,
    int n4)
{
    const int tid    = blockIdx.x * TPB + threadIdx.x;
    const int stride = gridDim.x * TPB;

    for (int i = tid; i < n4; i += stride) {
        const f32x4 v =
            __builtin_nontemporal_load(reinterpret_cast<const f32x4*>(x) + i);

        // per-lane amax of 4 elems, then reduce across the 8-lane group
        // (8 lanes x 4 elems = one 32-element quant block)
        float a = fmaxf(fmaxf(fabsf(v.x), fabsf(v.y)),
                        fmaxf(fabsf(v.z), fabsf(v.w)));
        a = fmaxf(a, __shfl_xor(a, 1, 8));
        a = fmaxf(a, __shfl_xor(a, 2, 8));
        a = fmaxf(a, __shfl_xor(a, 4, 8));

        // e8m0 = ceil(max(log2(a/6), -127)), exactly, branchless from bits:
        // for d > 2^-127:  e = biased_exp - 127 + (mantissa != 0)
        // for d <= 2^-127 (incl. 0 and subnormals): clamp to -127
        const float d = a / 6.0f;            // IEEE division (rounding matters)
        const unsigned ud = __float_as_uint(d);
        const int e8m0 = (ud <= 0x00400000u)
                           ? -127
                           : (int)(ud >> 23) - 127 + ((ud & 0x7fffffu) ? 1 : 0);

        // power-of-two scale -> all multiplies below are exact
        const float rscale = __uint_as_float(((unsigned)(127 - e8m0)) << 23); // 2^-e8m0
        const float scale  = (e8m0 <= -127)
                               ? __uint_as_float(0x00400000u)                 // 2^-127
                               : __uint_as_float(((unsigned)(e8m0 + 127)) << 23);

        f32x4 dq, ef;
        EncOut o;
        o = enc1(v.x, rscale, scale); dq.x = o.dq; ef.x = o.ef;
        o = enc1(v.y, rscale, scale); dq.y = o.dq; ef.y = o.ef;
        o = enc1(v.z, rscale, scale); dq.z = o.dq; ef.z = o.ef;
        o = enc1(v.w, rscale, scale); dq.w = o.dq; ef.w = o.ef;

        __builtin_nontemporal_store(dq, reinterpret_cast<f32x4*>(xdeq) + i);
        __builtin_nontemporal_store(ef, reinterpret_cast<f32x4*>(enc) + i);
        if ((i & 7) == 0)                    // first lane of each 8-lane group
            __builtin_nontemporal_store((float)(e8m0 + 127), scl + (i >> 3));
    }
}

extern "C" void kernel_launch(void* const* d_in, const int* in_sizes, int n_in,
                              void* d_out, int out_size, void* d_ws, size_t ws_size,
                              hipStream_t stream) {
    const float* x = (const float*)d_in[0];
    float* out = (float*)d_out;

    const int n  = in_sizes[0];        // 4096*8192
    const int n4 = n / 4;

    float* xdeq = out;
    float* enc  = out + (size_t)n;
    float* scl  = out + 2 * (size_t)n;

    int blocks = (n4 + TPB - 1) / TPB;
    if (blocks > 2048) blocks = 2048;  // grid-stride the rest (G11)

    e2m1_quant_kernel<<<blocks, TPB, 0, stream>>>(x, xdeq, enc, scl, n4);
}

// Round 8
// 71.506 us; speedup vs baseline: 1.1630x; 1.1630x over previous
//
#include <hip/hip_runtime.h>

// E2M1 (MXFP4-style) activation quantizer, block size 32, LAYER_MAX = 6.0.
// Outputs concatenated in d_out as float32:
//   [0, N)        x_deq
//   [N, 2N)       encoded (values 0..15, stored as float)
//   [2N, 2N+N/32) scale_uint8 (values 0..255, stored as float)
//
// FINAL (= round-6, 70.9us, 5.74 TB/s = 91% of 6.3 TB/s mixed ceiling):
//  - 1x float4 per lane, line-dense coalesced REGULAR loads
//    (nt loads measured -17% [round 7]; strided 2x-f32x4/lane -13% [round 5])
//  - nontemporal STORES (write-once streams >> 32MB L2): +17% [round 6]
//  - 8-lane group = one 32-elem quant block; amax via 3x shfl_xor
//  - exact bit-level e8m0 = ceil(log2(amax/6)); power-of-2 scale makes
//    x*rscale and m*scale exact -> bit-identical to numpy reference

typedef float f32x4 __attribute__((ext_vector_type(4)));

constexpr int TPB = 256;

struct EncOut { float dq, ef; };

__device__ __forceinline__ EncOut enc1(float xv, float rscale, float scale) {
    const float axn = fabsf(xv) * rscale;   // exact: power-of-2 scale
    const int ord = (axn > 0.25f) + (axn > 0.75f) + (axn > 1.25f) +
                    (axn > 1.75f) + (axn > 2.5f)  + (axn > 3.5f) +
                    (axn > 5.0f);
    // E2M1 table {0,0.5,1,1.5,2,3,4,6} without runtime-indexed array
    const float m = (ord <= 4) ? (float)ord * 0.5f
                     : (ord == 5 ? 3.0f : (ord == 6 ? 4.0f : 6.0f));
    const bool pos = xv > 0.0f;             // sign_bit = 1 for x <= 0
    EncOut o;
    o.ef = (float)(pos ? ord : ord + 8);
    o.dq = (pos ? m : -m) * scale;
    return o;
}

__global__ __launch_bounds__(TPB) void e2m1_quant_kernel(
    const float* __restrict__ x,
    float* __restrict__ xdeq,
    float* __restrict__ enc,
    float* __restrict__ scl,
    int n4)
{
    const int tid    = blockIdx.x * TPB + threadIdx.x;
    const int stride = gridDim.x * TPB;

    for (int i = tid; i < n4; i += stride) {
        const f32x4 v = reinterpret_cast<const f32x4*>(x)[i];  // regular load

        // per-lane amax of 4 elems, then reduce across the 8-lane group
        // (8 lanes x 4 elems = one 32-element quant block)
        float a = fmaxf(fmaxf(fabsf(v.x), fabsf(v.y)),
                        fmaxf(fabsf(v.z), fabsf(v.w)));
        a = fmaxf(a, __shfl_xor(a, 1, 8));
        a = fmaxf(a, __shfl_xor(a, 2, 8));
        a = fmaxf(a, __shfl_xor(a, 4, 8));

        // e8m0 = ceil(max(log2(a/6), -127)), exactly, branchless from bits:
        // for d > 2^-127:  e = biased_exp - 127 + (mantissa != 0)
        // for d <= 2^-127 (incl. 0 and subnormals): clamp to -127
        const float d = a / 6.0f;            // IEEE division (rounding matters)
        const unsigned ud = __float_as_uint(d);
        const int e8m0 = (ud <= 0x00400000u)
                           ? -127
                           : (int)(ud >> 23) - 127 + ((ud & 0x7fffffu) ? 1 : 0);

        // power-of-two scale -> all multiplies below are exact
        const float rscale = __uint_as_float(((unsigned)(127 - e8m0)) << 23); // 2^-e8m0
        const float scale  = (e8m0 <= -127)
                               ? __uint_as_float(0x00400000u)                 // 2^-127
                               : __uint_as_float(((unsigned)(e8m0 + 127)) << 23);

        f32x4 dq, ef;
        EncOut o;
        o = enc1(v.x, rscale, scale); dq.x = o.dq; ef.x = o.ef;
        o = enc1(v.y, rscale, scale); dq.y = o.dq; ef.y = o.ef;
        o = enc1(v.z, rscale, scale); dq.z = o.dq; ef.z = o.ef;
        o = enc1(v.w, rscale, scale); dq.w = o.dq; ef.w = o.ef;

        __builtin_nontemporal_store(dq, reinterpret_cast<f32x4*>(xdeq) + i);
        __builtin_nontemporal_store(ef, reinterpret_cast<f32x4*>(enc) + i);
        if ((i & 7) == 0)                    // first lane of each 8-lane group
            __builtin_nontemporal_store((float)(e8m0 + 127), scl + (i >> 3));
    }
}

extern "C" void kernel_launch(void* const* d_in, const int* in_sizes, int n_in,
                              void* d_out, int out_size, void* d_ws, size_t ws_size,
                              hipStream_t stream) {
    const float* x = (const float*)d_in[0];
    float* out = (float*)d_out;

    const int n  = in_sizes[0];        // 4096*8192
    const int n4 = n / 4;

    float* xdeq = out;
    float* enc  = out + (size_t)n;
    float* scl  = out + 2 * (size_t)n;

    int blocks = (n4 + TPB - 1) / TPB;
    if (blocks > 2048) blocks = 2048;  // grid-stride the rest (G11)

    e2m1_quant_kernel<<<blocks, TPB, 0, stream>>>(x, xdeq, enc, scl, n4);
}